// Round 1
// baseline (5423.436 us; speedup 1.0000x reference)
//
#include <hip/hip_runtime.h>
#include <math.h>

// Problem constants
#define NB   32
#define PB   6
#define CCH  128
#define TT   64
#define VV   25
#define SS   3
#define CIc  32
#define NP   (NB*PB)          // 192
#define PIX  (TT*VV)          // 1600
#define EPC  ((float)(NP*PIX))// 307200 elems per channel
#define NPIX (NP*PIX)         // 307200
static const size_t ETOT = (size_t)NP * CCH * PIX;   // 39,321,600
#define QK_KOFF (NP*CIc*PIX)  // offset of K half: 9,830,400 floats

// ---------------------------------------------------------------------------
// K1: per-s q/k conv: out q[(np*32+ci)*1600+pix], k at QK_KOFF + same
// ---------------------------------------------------------------------------
__global__ void conv_qk(const float* __restrict__ x, const float* __restrict__ w_in,
                        const float* __restrict__ b_in, float* __restrict__ qk, int s) {
    __shared__ float Ws[128][64];   // c-major, o contiguous -> broadcast b128 reads
    __shared__ float Bs[64];
    const int np  = blockIdx.x;
    const int tid = threadIdx.x;
    for (int i = tid; i < 128 * 64; i += 256) {
        int c = i >> 6, oo = i & 63;
        int row = (oo < 32) ? (s * 32 + oo) : (96 + s * 32 + (oo - 32));
        Ws[c][oo] = w_in[row * 128 + c];
    }
    if (tid < 64) {
        int oo = tid;
        int row = (oo < 32) ? (s * 32 + oo) : (96 + s * 32 + (oo - 32));
        Bs[oo] = b_in[row];
    }
    __syncthreads();
    const int pix = blockIdx.y * 256 + tid;
    if (pix >= PIX) return;
    const float* xp = x + (size_t)np * (CCH * PIX) + pix;
    float acc[64];
#pragma unroll
    for (int o = 0; o < 64; ++o) acc[o] = Bs[o];
    for (int c = 0; c < 128; ++c) {
        float xv = xp[(size_t)c * PIX];
        const float4* wr = (const float4*)Ws[c];
#pragma unroll
        for (int o4 = 0; o4 < 16; ++o4) {
            float4 w = wr[o4];
            acc[o4 * 4 + 0] += xv * w.x;
            acc[o4 * 4 + 1] += xv * w.y;
            acc[o4 * 4 + 2] += xv * w.z;
            acc[o4 * 4 + 3] += xv * w.w;
        }
    }
    float* qp = qk + (size_t)np * (CIc * PIX) + pix;
    float* kp = qk + QK_KOFF + (size_t)np * (CIc * PIX) + pix;
#pragma unroll
    for (int o = 0; o < 32; ++o) qp[(size_t)o * PIX] = acc[o];
#pragma unroll
    for (int o = 0; o < 32; ++o) kp[(size_t)o * PIX] = acc[32 + o];
}

// ---------------------------------------------------------------------------
// K2: scores -> att.  per (n,p) wg, fixed s.
// ---------------------------------------------------------------------------
__global__ void scores_k(const float* __restrict__ qk, const float* __restrict__ attb,
                         const float* __restrict__ alphat, float* __restrict__ att, int s) {
    __shared__ float Qs[PIX];
    __shared__ float Ks[PIX];
    const int np = blockIdx.x, tid = threadIdx.x;
    const float* qb = qk + (size_t)np * (CIc * PIX);
    const float* kb = qk + QK_KOFF + (size_t)np * (CIc * PIX);
    const int t = tid >> 2, q0 = (tid & 3) * 16;
    float acc[16] = {0};
    for (int ci = 0; ci < CIc; ++ci) {
        __syncthreads();
        for (int i = tid; i < PIX; i += 256) {
            Qs[i] = qb[(size_t)ci * PIX + i];
            Ks[i] = kb[(size_t)ci * PIX + i];
        }
        __syncthreads();
        for (int v = 0; v < VV; ++v) {
            float qv = Qs[t * VV + v];
#pragma unroll
            for (int j = 0; j < 16; ++j) acc[j] += qv * Ks[(q0 + j) * VV + v];
        }
    }
    const float alpha = alphat[s];
    const int n = np / PB, p = np % PB;
    const float* bp = attb + (size_t)s * (TT * TT) + t * TT;
    float* ap = att + ((size_t)(n * SS + s) * PB + p) * (TT * TT) + t * TT;
    const float inv = 1.0f / (float)(CIc * VV);
#pragma unroll
    for (int j = 0; j < 16; ++j) {
        ap[q0 + j] = bp[q0 + j] + tanhf(acc[j] * inv) * alpha;
    }
}

// ---------------------------------------------------------------------------
// K3: y_s[c,q,v] = sum_t x[c,t,v] * att_s[t,q]
// ---------------------------------------------------------------------------
__global__ void attn_apply(const float* __restrict__ x, const float* __restrict__ att,
                           float* __restrict__ y, int s) {
    __shared__ float As[TT * TT];
    const int np = blockIdx.x, tid = threadIdx.x;
    const int n = np / PB, p = np % PB;
    const float* ap = att + ((size_t)(n * SS + s) * PB + p) * (TT * TT);
    for (int i = tid; i < TT * TT; i += 256) As[i] = ap[i];
    __syncthreads();
    const int cv = blockIdx.y * 256 + tid;
    if (cv >= CCH * VV) return;
    const int c = cv / VV, v = cv - c * VV;
    const float* xp = x + (size_t)np * (CCH * PIX) + (size_t)c * PIX + v;
    float acc[64] = {0};
    for (int t = 0; t < TT; ++t) {
        float xv = xp[(size_t)t * VV];
        const float4* ar = (const float4*)&As[t * TT];
#pragma unroll
        for (int q4 = 0; q4 < 16; ++q4) {
            float4 a = ar[q4];
            acc[q4 * 4 + 0] += xv * a.x;
            acc[q4 * 4 + 1] += xv * a.y;
            acc[q4 * 4 + 2] += xv * a.z;
            acc[q4 * 4 + 3] += xv * a.w;
        }
    }
    float* yp = y + (size_t)np * (CCH * PIX) + (size_t)c * PIX + v;
#pragma unroll
    for (int q = 0; q < 64; ++q) yp[(size_t)q * VV] = acc[q];
}

// ---------------------------------------------------------------------------
// K4/K7: 64-output-chunk conv over Cin=128.  out (np, OC=128, pix), och=blockIdx.z
// ---------------------------------------------------------------------------
__global__ void conv64(const float* __restrict__ in, const float* __restrict__ W, int ldw,
                       const float* __restrict__ bias, float* __restrict__ out, int accflag) {
    __shared__ float Ws[128][64];
    __shared__ float Bs[64];
    const int np = blockIdx.x, tid = threadIdx.x, och = blockIdx.z;
    for (int i = tid; i < 128 * 64; i += 256) {
        int c = i >> 6, oo = i & 63;
        Ws[c][oo] = W[(size_t)(och * 64 + oo) * ldw + c];
    }
    if (tid < 64) Bs[tid] = bias ? bias[och * 64 + tid] : 0.0f;
    __syncthreads();
    const int pix = blockIdx.y * 256 + tid;
    if (pix >= PIX) return;
    const float* ip = in + (size_t)np * (CCH * PIX) + pix;
    float* op = out + (size_t)np * (CCH * PIX) + (size_t)och * 64 * PIX + pix;
    float acc[64];
    if (accflag) {
#pragma unroll
        for (int o = 0; o < 64; ++o) acc[o] = op[(size_t)o * PIX];
    } else {
#pragma unroll
        for (int o = 0; o < 64; ++o) acc[o] = Bs[o];
    }
    for (int c = 0; c < 128; ++c) {
        float xv = ip[(size_t)c * PIX];
        const float4* wr = (const float4*)Ws[c];
#pragma unroll
        for (int o4 = 0; o4 < 16; ++o4) {
            float4 w = wr[o4];
            acc[o4 * 4 + 0] += xv * w.x;
            acc[o4 * 4 + 1] += xv * w.y;
            acc[o4 * 4 + 2] += xv * w.z;
            acc[o4 * 4 + 3] += xv * w.w;
        }
    }
#pragma unroll
    for (int o = 0; o < 64; ++o) op[(size_t)o * PIX] = acc[o];
}

// ---------------------------------------------------------------------------
// BN stats: sum + sumsq per channel via block reduce + atomics
// ---------------------------------------------------------------------------
__global__ void bn_stats(const float* __restrict__ z, float* __restrict__ stats) {
    const int c = blockIdx.x, np = blockIdx.y, tid = threadIdx.x;
    const float* zp = z + ((size_t)np * CCH + c) * PIX;
    float s = 0.f, s2 = 0.f;
    for (int i = tid; i < PIX; i += 256) {
        float v = zp[i];
        s += v;
        s2 += v * v;
    }
    for (int off = 32; off; off >>= 1) {
        s  += __shfl_down(s, off);
        s2 += __shfl_down(s2, off);
    }
    __shared__ float ls[4], ls2[4];
    const int w = tid >> 6, lane = tid & 63;
    if (lane == 0) { ls[w] = s; ls2[w] = s2; }
    __syncthreads();
    if (tid == 0) {
        s  = ls[0] + ls[1] + ls[2] + ls[3];
        s2 = ls2[0] + ls2[1] + ls2[2] + ls2[3];
        atomicAdd(&stats[c], s);
        atomicAdd(&stats[128 + c], s2);
    }
}

__global__ void bn_finalize(const float* __restrict__ stats, const float* __restrict__ g,
                            const float* __restrict__ be, float* __restrict__ scsh) {
    const int c = threadIdx.x;
    float mean = stats[c] * (1.0f / EPC);
    float var  = stats[128 + c] * (1.0f / EPC) - mean * mean;
    float inv  = rsqrtf(var + 1e-5f);
    float sc   = g[c] * inv;
    scsh[c]       = sc;
    scsh[128 + c] = be[c] - mean * sc;
}

// ---------------------------------------------------------------------------
// out = leaky(x + z*scale + shift), float4 vectorized
// ---------------------------------------------------------------------------
__global__ void res_bn_leaky(const float4* __restrict__ xr, const float4* __restrict__ zr,
                             const float* __restrict__ scsh, float4* __restrict__ out, int n4) {
    const int i = blockIdx.x * 256 + threadIdx.x;
    if (i >= n4) return;
    const int row = i / 400;          // i*4/1600: global (np*128+c) row
    const int ch = row & 127;
    const float sc = scsh[ch], sh = scsh[128 + ch];
    float4 a = xr[i], b = zr[i], r;
    r.x = a.x + fmaf(b.x, sc, sh);
    r.y = a.y + fmaf(b.y, sc, sh);
    r.z = a.z + fmaf(b.z, sc, sh);
    r.w = a.w + fmaf(b.w, sc, sh);
    r.x = r.x >= 0.f ? r.x : 0.1f * r.x;
    r.y = r.y >= 0.f ? r.y : 0.1f * r.y;
    r.z = r.z >= 0.f ? r.z : 0.1f * r.z;
    r.w = r.w >= 0.f ? r.w : 0.1f * r.w;
    out[i] = r;
}

// ---------------------------------------------------------------------------
struct Weights {
    const float *alphat, *w_in, *b_in, *w_out, *b_out, *g_out, *be_out;
    const float *w_ff, *b_ff, *g_ff, *be_ff;
};

static void run_block(const float* X, const float* attb, float* OUT,
                      float* A, float* B, float* ATT, float* STATS,
                      const Weights& w, hipStream_t stream) {
    const int n4 = (int)(ETOT / 4);   // 9,830,400
    for (int s = 0; s < SS; ++s) {
        conv_qk<<<dim3(NP, 7), 256, 0, stream>>>(X, w.w_in, w.b_in, A, s);
        scores_k<<<dim3(NP), 256, 0, stream>>>(A, attb, w.alphat, ATT, s);
    }
    for (int s = 0; s < SS; ++s) {
        attn_apply<<<dim3(NP, 13), 256, 0, stream>>>(X, ATT, B, s);
        conv64<<<dim3(NP, 7, 2), 256, 0, stream>>>(B, w.w_out + s * 128, SS * CCH,
                                                   (s == 0) ? w.b_out : nullptr, A, s != 0);
    }
    hipMemsetAsync(STATS, 0, 256 * sizeof(float), stream);
    bn_stats<<<dim3(CCH, NP), 256, 0, stream>>>(A, STATS);
    bn_finalize<<<1, 128, 0, stream>>>(STATS, w.g_out, w.be_out, STATS + 256);
    res_bn_leaky<<<n4 / 256, 256, 0, stream>>>((const float4*)X, (const float4*)A,
                                               STATS + 256, (float4*)B, n4);   // B = y1
    conv64<<<dim3(NP, 7, 2), 256, 0, stream>>>(B, w.w_ff, CCH, w.b_ff, A, 0);  // A = z2
    hipMemsetAsync(STATS, 0, 256 * sizeof(float), stream);
    bn_stats<<<dim3(CCH, NP), 256, 0, stream>>>(A, STATS);
    bn_finalize<<<1, 128, 0, stream>>>(STATS, w.g_ff, w.be_ff, STATS + 256);
    res_bn_leaky<<<n4 / 256, 256, 0, stream>>>((const float4*)B, (const float4*)A,
                                               STATS + 256, (float4*)OUT, n4);
}

extern "C" void kernel_launch(void* const* d_in, const int* in_sizes, int n_in,
                              void* d_out, int out_size, void* d_ws, size_t ws_size,
                              hipStream_t stream) {
    const float* x     = (const float*)d_in[0];
    const float* att1  = (const float*)d_in[1];
    const float* att2  = (const float*)d_in[2];
    Weights w;
    w.alphat = (const float*)d_in[3];
    w.w_in   = (const float*)d_in[4];
    w.b_in   = (const float*)d_in[5];
    w.w_out  = (const float*)d_in[6];
    w.b_out  = (const float*)d_in[7];
    w.g_out  = (const float*)d_in[8];
    w.be_out = (const float*)d_in[9];
    w.w_ff   = (const float*)d_in[10];
    w.b_ff   = (const float*)d_in[11];
    w.g_ff   = (const float*)d_in[12];
    w.be_ff  = (const float*)d_in[13];

    float* A     = (float*)d_ws;                       // 39,321,600 floats
    float* B     = A + ETOT;                           // 39,321,600 floats
    float* ATT   = B + ETOT;                           // 2,359,296 floats
    float* STATS = ATT + (size_t)NB * SS * PB * TT * TT; // 512 floats

    float* out = (float*)d_out;
    // Block 1: x -> d_out ; Block 2: d_out -> d_out (final kernel reads only A/B)
    run_block(x, att1, out, A, B, ATT, STATS, w, stream);
    run_block(out, att2, out, A, B, ATT, STATS, w, stream);
}

// Round 2
// 2336.959 us; speedup vs baseline: 2.3207x; 2.3207x over previous
//
#include <hip/hip_runtime.h>
#include <hip/hip_bf16.h>
#include <math.h>

// Problem constants
#define NPB  192            // N*P = 32*6
#define CCH  128
#define TT   64
#define VV   25
#define PIX  1600           // T*V
#define SS   3
#define EPC  307200.0f      // elems per channel for BN (192*1600)
static const size_t ETOT = (size_t)NPB * CCH * PIX;   // 39,321,600

typedef __attribute__((ext_vector_type(4))) float f32x4;
typedef __attribute__((ext_vector_type(8))) short short8;

__device__ __forceinline__ ushort f2bf(float f) {
    __hip_bfloat16 h = __float2bfloat16(f);
    return __builtin_bit_cast(unsigned short, h);
}
__device__ __forceinline__ float bf2f(ushort u) {
    unsigned int x = ((unsigned int)u) << 16;
    return __builtin_bit_cast(float, x);
}

// ---------------------------------------------------------------------------
// Weight prep: permute w_in rows to [q0|k0|q1|k1|q2|k2] (64-chunks), cvt bf16
// ---------------------------------------------------------------------------
__global__ void wprep(const float* __restrict__ w_in, const float* __restrict__ b_in,
                      const float* __restrict__ w_out, const float* __restrict__ w_ff,
                      ushort* __restrict__ Wp, float* __restrict__ bp,
                      ushort* __restrict__ Wo, ushort* __restrict__ Wf) {
    int i = blockIdx.x * 256 + threadIdx.x;   // grid covers 49152
    if (i < 192 * 128) {
        int r = i >> 7, c = i & 127;
        int s = r / 64, j = r % 64;
        int src = (j < 32) ? (s * 32 + j) : (96 + s * 32 + (j - 32));
        Wp[i] = f2bf(w_in[src * 128 + c]);
        if (c == 0) bp[r] = b_in[src];
    }
    if (i < 128 * 384) Wo[i] = f2bf(w_out[i]);
    if (i < 128 * 128) Wf[i] = f2bf(w_ff[i]);
}

// ---------------------------------------------------------------------------
// remap: xr[np][c][v*64+t] = bf16(x[np][c][t*25+v])
// ---------------------------------------------------------------------------
__global__ void remap_x(const float* __restrict__ x, ushort* __restrict__ xr) {
    size_t o = ((size_t)blockIdx.x * 256 + threadIdx.x) * 4;
    size_t row = o / PIX;
    int p = (int)(o % PIX);           // v*64 + t0, t0 multiple of 4
    int v = p >> 6, t0 = p & 63;
    const float* xp = x + row * PIX;
    uint2 u;
    u.x = (uint)f2bf(xp[(t0 + 0) * 25 + v]) | ((uint)f2bf(xp[(t0 + 1) * 25 + v]) << 16);
    u.y = (uint)f2bf(xp[(t0 + 2) * 25 + v]) | ((uint)f2bf(xp[(t0 + 3) * 25 + v]) << 16);
    *(uint2*)(xr + o) = u;
}

// ---------------------------------------------------------------------------
// MFMA conv GEMM: out[np][obase+o][pix] (+)= sum_{k<128} W[o][k]*in[np][k][pix]
//  o-chunk 64 (blockIdx.z), pix tile 128 (blockIdx.y), K=128 in 2 chunks of 64
//  A = W (m=o), B = in (n=pix), 16x16x32 bf16 MFMA
// ---------------------------------------------------------------------------
__global__ __launch_bounds__(256)
void gemm_conv(const void* __restrict__ inp, int in_bf16,
               const ushort* __restrict__ W, int ldw,
               const float* __restrict__ bias,
               void* __restrict__ outp, int out_bf16, int out_ch,
               int accflag)
{
    __shared__ ushort Wt[64 * 72];
    __shared__ ushort Xt[128 * 72];
    const int np = blockIdx.x;
    const int pixbase = blockIdx.y * 128;
    const int obase = blockIdx.z * 64;
    const int tid = threadIdx.x;
    const int wave = tid >> 6, lane = tid & 63;
    const int quad = lane >> 4, l16 = lane & 15;
    const int wPix = wave * 32;

    f32x4 acc[4][2];
    if (accflag) {
        const float* op = (const float*)outp + ((size_t)np * out_ch + obase) * PIX + pixbase;
#pragma unroll
        for (int ms = 0; ms < 4; ++ms)
#pragma unroll
            for (int ns = 0; ns < 2; ++ns) {
                int pl = wPix + ns * 16 + l16;
                bool valid = (pixbase + pl) < PIX;
#pragma unroll
                for (int r = 0; r < 4; ++r) {
                    int ol = ms * 16 + quad * 4 + r;
                    acc[ms][ns][r] = valid ? op[(size_t)ol * PIX + pl] : 0.f;
                }
            }
    } else {
#pragma unroll
        for (int ms = 0; ms < 4; ++ms) {
            float bv[4];
#pragma unroll
            for (int r = 0; r < 4; ++r) {
                int ol = ms * 16 + quad * 4 + r;
                bv[r] = bias ? bias[obase + ol] : 0.f;
            }
#pragma unroll
            for (int ns = 0; ns < 2; ++ns)
#pragma unroll
                for (int r = 0; r < 4; ++r) acc[ms][ns][r] = bv[r];
        }
    }

    const ushort* inb = (const ushort*)inp;
    const float* inf = (const float*)inp;
    const size_t in_off = (size_t)np * 128 * PIX;

    for (int kc = 0; kc < 2; ++kc) {
        const int kbase = kc * 64;
        // ---- stage Wt[o][k] (64x64 bf16), rows padded to 72
        {
            int o = tid >> 2, seg = tid & 3;
            const ushort* src = W + (size_t)(obase + o) * ldw + kbase + seg * 16;
            uint4 a = *(const uint4*)src;
            uint4 b = *(const uint4*)(src + 8);
            *(uint4*)&Wt[o * 72 + seg * 16] = a;
            *(uint4*)&Wt[o * 72 + seg * 16 + 8] = b;
        }
        // ---- stage Xt[p][k] transposed (128 pix x 64 k), b32-packed writes
        {
            int cp = tid & 31, rq = tid >> 5;
            int c = cp * 2;
            int p0 = rq * 16;
            bool valid = (pixbase + p0) < PIX;
            if (in_bf16) {
                uint ra[8], rb[8];
                if (valid) {
                    const ushort* s0 = inb + in_off + (size_t)(kbase + c) * PIX + pixbase + p0;
                    const ushort* s1 = s0 + PIX;
                    *(uint4*)&ra[0] = *(const uint4*)s0;
                    *(uint4*)&ra[4] = *(const uint4*)(s0 + 8);
                    *(uint4*)&rb[0] = *(const uint4*)s1;
                    *(uint4*)&rb[4] = *(const uint4*)(s1 + 8);
                } else {
#pragma unroll
                    for (int h = 0; h < 8; ++h) { ra[h] = 0; rb[h] = 0; }
                }
#pragma unroll
                for (int h = 0; h < 8; ++h) {
                    uint lo = ra[h], hi = rb[h];
                    *(uint*)&Xt[(p0 + 2 * h) * 72 + c] = (lo & 0xffffu) | (hi << 16);
                    *(uint*)&Xt[(p0 + 2 * h + 1) * 72 + c] = (lo >> 16) | (hi & 0xffff0000u);
                }
            } else {
                if (valid) {
                    const float* s0 = inf + in_off + (size_t)(kbase + c) * PIX + pixbase + p0;
                    const float* s1 = s0 + PIX;
#pragma unroll
                    for (int b4 = 0; b4 < 4; ++b4) {
                        float4 u = ((const float4*)s0)[b4];
                        float4 w4 = ((const float4*)s1)[b4];
                        int p = p0 + b4 * 4;
                        *(uint*)&Xt[(p + 0) * 72 + c] = (uint)f2bf(u.x) | ((uint)f2bf(w4.x) << 16);
                        *(uint*)&Xt[(p + 1) * 72 + c] = (uint)f2bf(u.y) | ((uint)f2bf(w4.y) << 16);
                        *(uint*)&Xt[(p + 2) * 72 + c] = (uint)f2bf(u.z) | ((uint)f2bf(w4.z) << 16);
                        *(uint*)&Xt[(p + 3) * 72 + c] = (uint)f2bf(u.w) | ((uint)f2bf(w4.w) << 16);
                    }
                } else {
#pragma unroll
                    for (int h = 0; h < 16; ++h) *(uint*)&Xt[(p0 + h) * 72 + c] = 0;
                }
            }
        }
        __syncthreads();
        // ---- compute: 2 k-steps of 32
#pragma unroll
        for (int ks = 0; ks < 2; ++ks) {
            const int kk = ks * 32;
            short8 a[4], b[2];
#pragma unroll
            for (int ms = 0; ms < 4; ++ms)
                a[ms] = *(const short8*)&Wt[(ms * 16 + l16) * 72 + kk + quad * 8];
#pragma unroll
            for (int ns = 0; ns < 2; ++ns)
                b[ns] = *(const short8*)&Xt[(wPix + ns * 16 + l16) * 72 + kk + quad * 8];
#pragma unroll
            for (int ms = 0; ms < 4; ++ms)
#pragma unroll
                for (int ns = 0; ns < 2; ++ns)
                    acc[ms][ns] = __builtin_amdgcn_mfma_f32_16x16x32_bf16(a[ms], b[ns], acc[ms][ns], 0, 0, 0);
        }
        __syncthreads();
    }

    // ---- epilogue
    if (out_bf16) {
        ushort* op = (ushort*)outp + ((size_t)np * out_ch + obase) * PIX + pixbase;
#pragma unroll
        for (int ms = 0; ms < 4; ++ms)
#pragma unroll
            for (int ns = 0; ns < 2; ++ns) {
                int pl = wPix + ns * 16 + l16;
                if (pixbase + pl >= PIX) continue;
#pragma unroll
                for (int r = 0; r < 4; ++r) {
                    int ol = ms * 16 + quad * 4 + r;
                    op[(size_t)ol * PIX + pl] = f2bf(acc[ms][ns][r]);
                }
            }
    } else {
        float* op = (float*)outp + ((size_t)np * out_ch + obase) * PIX + pixbase;
#pragma unroll
        for (int ms = 0; ms < 4; ++ms)
#pragma unroll
            for (int ns = 0; ns < 2; ++ns) {
                int pl = wPix + ns * 16 + l16;
                if (pixbase + pl >= PIX) continue;
#pragma unroll
                for (int r = 0; r < 4; ++r) {
                    int ol = ms * 16 + quad * 4 + r;
                    op[(size_t)ol * PIX + pl] = acc[ms][ns][r];
                }
            }
    }
}

// ---------------------------------------------------------------------------
// scores: att[n,s,p,t,q] = attb + tanh(scores/800)*alpha ; QK bf16, pix'=(v,t)
// ---------------------------------------------------------------------------
__global__ __launch_bounds__(256)
void scores_k(const ushort* __restrict__ qk, const float* __restrict__ attb,
              const float* __restrict__ alphat, float* __restrict__ att) {
    __shared__ float Qs[PIX];
    __shared__ float Ks[PIX];
    const int np = blockIdx.x, s = blockIdx.y, tid = threadIdx.x;
    const ushort* qb = qk + ((size_t)np * 192 + s * 64) * PIX;
    const ushort* kb = qb + (size_t)32 * PIX;
    const int t = tid >> 2, q0 = (tid & 3) * 16;
    float acc[16] = {0};
    for (int ci = 0; ci < 32; ++ci) {
        __syncthreads();
        for (int i = tid; i < PIX; i += 256) {
            Qs[i] = bf2f(qb[(size_t)ci * PIX + i]);
            Ks[i] = bf2f(kb[(size_t)ci * PIX + i]);
        }
        __syncthreads();
        for (int v = 0; v < VV; ++v) {
            float qv = Qs[v * 64 + t];
            const float4* kr = (const float4*)&Ks[v * 64 + q0];
            float4 k0 = kr[0], k1 = kr[1], k2 = kr[2], k3 = kr[3];
            acc[0] += qv * k0.x;  acc[1] += qv * k0.y;  acc[2] += qv * k0.z;  acc[3] += qv * k0.w;
            acc[4] += qv * k1.x;  acc[5] += qv * k1.y;  acc[6] += qv * k1.z;  acc[7] += qv * k1.w;
            acc[8] += qv * k2.x;  acc[9] += qv * k2.y;  acc[10] += qv * k2.z; acc[11] += qv * k2.w;
            acc[12] += qv * k3.x; acc[13] += qv * k3.y; acc[14] += qv * k3.z; acc[15] += qv * k3.w;
        }
    }
    const float alpha = alphat[s];
    const int n = np / 6, p = np % 6;
    const float* bp2 = attb + (size_t)s * 4096 + t * 64;
    float* ap = att + ((size_t)(n * SS + s) * 6 + p) * 4096 + t * 64;
    const float inv = 1.0f / 800.0f;
#pragma unroll
    for (int j = 0; j < 16; ++j)
        ap[q0 + j] = bp2[q0 + j] + tanhf(acc[j] * inv) * alpha;
}

// ---------------------------------------------------------------------------
// attn MFMA: y[np][c][v*64+q] = sum_t xr[np][c][v*64+t] * att[t][q]  (bf16 out)
// ---------------------------------------------------------------------------
__global__ __launch_bounds__(256)
void attn_mm(const ushort* __restrict__ xr, const float* __restrict__ att,
             ushort* __restrict__ y, int s)
{
    __shared__ ushort Xa[128 * 72];
    __shared__ ushort Ta[64 * 72];
    const int np = blockIdx.x, v = blockIdx.y, tid = threadIdx.x;
    const int wave = tid >> 6, lane = tid & 63;
    const int quad = lane >> 4, l16 = lane & 15;
    const int cH = (wave & 1) * 64, qH = (wave >> 1) * 32;
    const int n = np / 6, p = np % 6;
    // stage Xa[c][t]: direct coalesced from xr
    {
        int c = tid >> 1, half = tid & 1;
        const ushort* src = xr + ((size_t)np * 128 + c) * PIX + v * 64 + half * 32;
        uint4 a = *(const uint4*)src;
        uint4 b = *(const uint4*)(src + 8);
        uint4 c0 = *(const uint4*)(src + 16);
        uint4 d = *(const uint4*)(src + 24);
        *(uint4*)&Xa[c * 72 + half * 32] = a;
        *(uint4*)&Xa[c * 72 + half * 32 + 8] = b;
        *(uint4*)&Xa[c * 72 + half * 32 + 16] = c0;
        *(uint4*)&Xa[c * 72 + half * 32 + 24] = d;
    }
    // stage Ta[q][t] = att[t][q] (bf16, b32-packed)
    {
        int q = tid >> 2, seg = tid & 3;
        const float* ab = att + ((size_t)(n * SS + s) * 6 + p) * 4096;
#pragma unroll
        for (int i2 = 0; i2 < 8; ++i2) {
            int t0 = seg * 16 + i2 * 2;
            uint w = (uint)f2bf(ab[t0 * 64 + q]) | ((uint)f2bf(ab[(t0 + 1) * 64 + q]) << 16);
            *(uint*)&Ta[q * 72 + t0] = w;
        }
    }
    __syncthreads();
    f32x4 acc[4][2];
#pragma unroll
    for (int ms = 0; ms < 4; ++ms)
#pragma unroll
        for (int ns = 0; ns < 2; ++ns)
#pragma unroll
            for (int r = 0; r < 4; ++r) acc[ms][ns][r] = 0.f;
#pragma unroll
    for (int ks = 0; ks < 2; ++ks) {
        const int kk = ks * 32;
        short8 a[4], b[2];
#pragma unroll
        for (int ms = 0; ms < 4; ++ms)
            a[ms] = *(const short8*)&Xa[(cH + ms * 16 + l16) * 72 + kk + quad * 8];
#pragma unroll
        for (int ns = 0; ns < 2; ++ns)
            b[ns] = *(const short8*)&Ta[(qH + ns * 16 + l16) * 72 + kk + quad * 8];
#pragma unroll
        for (int ms = 0; ms < 4; ++ms)
#pragma unroll
            for (int ns = 0; ns < 2; ++ns)
                acc[ms][ns] = __builtin_amdgcn_mfma_f32_16x16x32_bf16(a[ms], b[ns], acc[ms][ns], 0, 0, 0);
    }
    ushort* yp = y + (size_t)np * 128 * PIX + v * 64;
#pragma unroll
    for (int ms = 0; ms < 4; ++ms)
#pragma unroll
        for (int ns = 0; ns < 2; ++ns) {
            int q = qH + ns * 16 + l16;
#pragma unroll
            for (int r = 0; r < 4; ++r) {
                int c = cH + ms * 16 + quad * 4 + r;
                yp[(size_t)c * PIX + q] = f2bf(acc[ms][ns][r]);
            }
        }
}

// ---------------------------------------------------------------------------
// BN stats + finalize
// ---------------------------------------------------------------------------
__global__ void bn_stats(const float* __restrict__ z, float* __restrict__ stats) {
    const int c = blockIdx.x, np = blockIdx.y, tid = threadIdx.x;
    const float* zp = z + ((size_t)np * CCH + c) * PIX;
    float s = 0.f, s2 = 0.f;
    for (int i = tid; i < PIX; i += 256) {
        float v = zp[i];
        s += v; s2 += v * v;
    }
    for (int off = 32; off; off >>= 1) {
        s += __shfl_down(s, off);
        s2 += __shfl_down(s2, off);
    }
    __shared__ float ls[4], ls2[4];
    const int w = tid >> 6, lane = tid & 63;
    if (lane == 0) { ls[w] = s; ls2[w] = s2; }
    __syncthreads();
    if (tid == 0) {
        s = ls[0] + ls[1] + ls[2] + ls[3];
        s2 = ls2[0] + ls2[1] + ls2[2] + ls2[3];
        atomicAdd(&stats[c], s);
        atomicAdd(&stats[128 + c], s2);
    }
}

__global__ void bn_finalize(const float* __restrict__ stats, const float* __restrict__ g,
                            const float* __restrict__ be, float* __restrict__ scsh) {
    const int c = threadIdx.x;
    float mean = stats[c] * (1.0f / EPC);
    float var = stats[128 + c] * (1.0f / EPC) - mean * mean;
    float inv = rsqrtf(var + 1e-5f);
    float sc = g[c] * inv;
    scsh[c] = sc;
    scsh[128 + c] = be[c] - mean * sc;
}

// ---------------------------------------------------------------------------
// res1: y1[i(orig)] = leaky(x[i] + bn(Z'[perm(i)]))   (Z' in pix' order)
// ---------------------------------------------------------------------------
__global__ void res_bn_g(const float* __restrict__ x, const float* __restrict__ z,
                         const float* __restrict__ scsh, float* __restrict__ out) {
    size_t i = ((size_t)blockIdx.x * 256 + threadIdx.x) * 4;
    size_t row = i / PIX;
    int p = (int)(i % PIX);
    int ch = (int)(row & 127);
    float sc = scsh[ch], sh = scsh[128 + ch];
    const float* zr = z + row * PIX;
    float4 a = *(const float4*)(x + i);
    float xin[4] = {a.x, a.y, a.z, a.w};
    float4 r;
    float ro[4];
#pragma unroll
    for (int j = 0; j < 4; ++j) {
        int pp = p + j;
        int t = pp / 25, vv = pp - t * 25;
        float zz = zr[vv * 64 + t];
        float val = xin[j] + fmaf(zz, sc, sh);
        ro[j] = val >= 0.f ? val : 0.1f * val;
    }
    r.x = ro[0]; r.y = ro[1]; r.z = ro[2]; r.w = ro[3];
    *(float4*)(out + i) = r;
}

// ---------------------------------------------------------------------------
// res2: out = leaky(y1 + bn(z2)), all orig order, float4
// ---------------------------------------------------------------------------
__global__ void res_bn_l(const float4* __restrict__ xr, const float4* __restrict__ zr,
                         const float* __restrict__ scsh, float4* __restrict__ out) {
    int i = blockIdx.x * 256 + threadIdx.x;
    int row = i / 400;
    int ch = row & 127;
    float sc = scsh[ch], sh = scsh[128 + ch];
    float4 a = xr[i], b = zr[i], r;
    r.x = a.x + fmaf(b.x, sc, sh);
    r.y = a.y + fmaf(b.y, sc, sh);
    r.z = a.z + fmaf(b.z, sc, sh);
    r.w = a.w + fmaf(b.w, sc, sh);
    r.x = r.x >= 0.f ? r.x : 0.1f * r.x;
    r.y = r.y >= 0.f ? r.y : 0.1f * r.y;
    r.z = r.z >= 0.f ? r.z : 0.1f * r.z;
    r.w = r.w >= 0.f ? r.w : 0.1f * r.w;
    out[i] = r;
}

// ---------------------------------------------------------------------------
struct Ctx {
    ushort *xr, *Wp, *Wo, *Wf;
    float *bp;
    float *R1, *R0, *ATT, *STATS;
    const float *alphat, *b_out, *g_out, *be_out, *b_ff, *g_ff, *be_ff;
};

static void run_block(const float* X, const float* attb, float* OUT,
                      const Ctx& c, hipStream_t stream) {
    const int EG = 38400;   // 39,321,600 / (256*4)
    remap_x<<<EG, 256, 0, stream>>>(X, c.xr);
    // q/k conv -> QK (bf16, in R1), channels [q0|k0|q1|k1|q2|k2]
    gemm_conv<<<dim3(NPB, 13, 3), 256, 0, stream>>>(c.xr, 1, c.Wp, 128, c.bp,
                                                    (void*)c.R1, 1, 192, 0);
    scores_k<<<dim3(NPB, 3), 256, 0, stream>>>((const ushort*)c.R1, attb, c.alphat, c.ATT);
    // per-s: attention apply (bf16 y in R1) then accumulate conv_out into Z (R0)
    for (int s = 0; s < SS; ++s) {
        attn_mm<<<dim3(NPB, VV), 256, 0, stream>>>(c.xr, c.ATT, (ushort*)c.R1, s);
        gemm_conv<<<dim3(NPB, 13, 2), 256, 0, stream>>>((const ushort*)c.R1, 1,
                                                        c.Wo + s * 128, 384,
                                                        (s == 0) ? c.b_out : nullptr,
                                                        (void*)c.R0, 0, 128, s != 0);
    }
    hipMemsetAsync(c.STATS, 0, 256 * sizeof(float), stream);
    bn_stats<<<dim3(CCH, NPB), 256, 0, stream>>>(c.R0, c.STATS);
    bn_finalize<<<1, 128, 0, stream>>>(c.STATS, c.g_out, c.be_out, c.STATS + 256);
    res_bn_g<<<EG, 256, 0, stream>>>(X, c.R0, c.STATS + 256, c.R1);   // y1 fp32 in R1
    gemm_conv<<<dim3(NPB, 13, 2), 256, 0, stream>>>(c.R1, 0, c.Wf, 128, c.b_ff,
                                                    (void*)c.R0, 0, 128, 0);  // z2 in R0
    hipMemsetAsync(c.STATS, 0, 256 * sizeof(float), stream);
    bn_stats<<<dim3(CCH, NPB), 256, 0, stream>>>(c.R0, c.STATS);
    bn_finalize<<<1, 128, 0, stream>>>(c.STATS, c.g_ff, c.be_ff, c.STATS + 256);
    res_bn_l<<<EG, 256, 0, stream>>>((const float4*)c.R1, (const float4*)c.R0,
                                     c.STATS + 256, (float4*)OUT);
}

extern "C" void kernel_launch(void* const* d_in, const int* in_sizes, int n_in,
                              void* d_out, int out_size, void* d_ws, size_t ws_size,
                              hipStream_t stream) {
    const float* x = (const float*)d_in[0];
    const float* att1 = (const float*)d_in[1];
    const float* att2 = (const float*)d_in[2];
    Ctx c;
    c.alphat = (const float*)d_in[3];
    const float* w_in = (const float*)d_in[4];
    const float* b_in = (const float*)d_in[5];
    const float* w_out = (const float*)d_in[6];
    c.b_out = (const float*)d_in[7];
    c.g_out = (const float*)d_in[8];
    c.be_out = (const float*)d_in[9];
    const float* w_ff = (const float*)d_in[10];
    c.b_ff = (const float*)d_in[11];
    c.g_ff = (const float*)d_in[12];
    c.be_ff = (const float*)d_in[13];

    char* ws = (char*)d_ws;
    size_t off = 0;
    c.xr = (ushort*)(ws + off);   off += ETOT * 2;                    //  78.6 MB
    c.R1 = (float*)(ws + off);    off += ETOT * 4;                    // 157.3 MB
    c.R0 = (float*)(ws + off);    off += ETOT * 4;                    // 157.3 MB
    c.ATT = (float*)(ws + off);   off += (size_t)32 * 3 * 6 * 4096 * 4; // 9.4 MB
    c.STATS = (float*)(ws + off); off += 512 * 4;
    c.Wp = (ushort*)(ws + off);   off += 192 * 128 * 2;
    c.bp = (float*)(ws + off);    off += 192 * 4;
    c.Wo = (ushort*)(ws + off);   off += 128 * 384 * 2;
    c.Wf = (ushort*)(ws + off);   off += 128 * 128 * 2;

    wprep<<<192, 256, 0, stream>>>(w_in, b_in, w_out, w_ff, c.Wp, c.bp, c.Wo, c.Wf);

    float* out = (float*)d_out;
    run_block(x, att1, out, c, stream);
    run_block(out, att2, out, c, stream);
}